// Round 4
// baseline (580.719 us; speedup 1.0000x reference)
//
#include <hip/hip_runtime.h>

// SAGE layer: out = relu(x @ W_self + (segment_sum(x[src], dst)/max(deg,1)) @ W_neigh + b)
//
// R3 = R2 pipeline with the fallback-path typo fixed (&degf mangled to °f).
//   1. k_tobf16:   x (f32) -> xb (bf16)               [halves gather volume]
//   2. k_bincount: edges per 256-row dst bucket        [LDS hist, few global atomics]
//   3. k_bscan:    exclusive scan -> bucket_start/cur  [1 block]
//   4. k_bpart:    chunk-in-LDS partition; per-(block,bucket) single cursor atomic;
//                  payload (src<<8)|dst_local written in contiguous runs -> L2-merged lines
//   5. k_baggr:    block per bucket; 64KB LDS fp32 acc; ds atomics; normalize -> hb (bf16)
//   6. k_gemm_mfma: A=[xb|hb] K=128, W=[Ws;Wn] bf16 MFMA, bias+relu
// Fallback (small ws): R0 atomic scatter + shfl gemm.

constexpr int F = 64;
constexpr int BROWS = 256;   // dst rows per bucket
constexpr int MAXNB = 512;   // max buckets (num_dst <= 131072)
constexpr int CH = 8192;     // edges per partition block
constexpr int LDK = 136;     // 128 + 8 pad (bf16 elems), 272B row stride

typedef __attribute__((ext_vector_type(8))) short short8;
typedef __attribute__((ext_vector_type(4))) float float4v;

__device__ inline unsigned short f2bf(float f) {
    union { float f; unsigned u; } c; c.f = f;
    unsigned u = c.u;
    return (unsigned short)((u + 0x7FFFu + ((u >> 16) & 1u)) >> 16);  // RNE
}
__device__ inline float bf2f(unsigned short h) {
    union { unsigned u; float f; } c; c.u = (unsigned)h << 16;
    return c.f;
}

// ---------------- 1. convert x to bf16 ----------------
__global__ __launch_bounds__(256) void k_tobf16(const float* __restrict__ x,
                                                unsigned short* __restrict__ xb, long n4) {
    for (long i = (long)blockIdx.x * 256 + threadIdx.x; i < n4; i += (long)gridDim.x * 256) {
        float4 v = ((const float4*)x)[i];
        ushort4 o;
        o.x = f2bf(v.x); o.y = f2bf(v.y); o.z = f2bf(v.z); o.w = f2bf(v.w);
        ((ushort4*)xb)[i] = o;
    }
}

// ---------------- 2. bucket histogram ----------------
__global__ __launch_bounds__(256) void k_bincount(const int* __restrict__ dst,
                                                  int* __restrict__ bcnt, int n_edges) {
    __shared__ int h[MAXNB];
    for (int i = threadIdx.x; i < MAXNB; i += 256) h[i] = 0;
    __syncthreads();
    for (int e = blockIdx.x * 256 + threadIdx.x; e < n_edges; e += gridDim.x * 256)
        atomicAdd(&h[dst[e] >> 8], 1);
    __syncthreads();
    for (int i = threadIdx.x; i < MAXNB; i += 256)
        if (h[i]) atomicAdd(&bcnt[i], h[i]);
}

// ---------------- 3. scan ----------------
__global__ __launch_bounds__(512) void k_bscan(const int* __restrict__ bcnt,
                                               int* __restrict__ bstart,
                                               int* __restrict__ bcur, int nb) {
    __shared__ int buf[MAXNB];
    int t = threadIdx.x;
    int v = bcnt[t];
    buf[t] = v; __syncthreads();
    for (int off = 1; off < MAXNB; off <<= 1) {
        int tv = (t >= off) ? buf[t - off] : 0;
        __syncthreads();
        buf[t] += tv;
        __syncthreads();
    }
    int ex = buf[t] - v;
    if (t < nb) { bstart[t] = ex; bcur[t] = ex; }
    if (t == MAXNB - 1) bstart[nb] = buf[MAXNB - 1];
}

// ---------------- 4. partition (chunk-in-LDS, run-contiguous writes) ----------------
__global__ __launch_bounds__(512) void k_bpart(const int* __restrict__ src,
                                               const int* __restrict__ dst,
                                               int* __restrict__ bcur,
                                               unsigned* __restrict__ pay, int n_edges) {
    __shared__ unsigned pl[CH];
    __shared__ unsigned short bk[CH];
    __shared__ int hist[MAXNB];
    __shared__ int base[MAXNB];
    __shared__ int lcur[MAXNB];
    int t = threadIdx.x;
    int e0 = blockIdx.x * CH;
    for (int i = t; i < MAXNB; i += 512) { hist[i] = 0; lcur[i] = 0; }
    __syncthreads();
    for (int i = t; i < CH; i += 512) {
        int e = e0 + i;
        if (e < n_edges) {
            int d = dst[e];
            int b = d >> 8;
            pl[i] = ((unsigned)src[e] << 8) | (unsigned)(d & 255);
            bk[i] = (unsigned short)b;
            atomicAdd(&hist[b], 1);
        }
    }
    __syncthreads();
    for (int i = t; i < MAXNB; i += 512)
        if (hist[i]) base[i] = atomicAdd(&bcur[i], hist[i]);
    __syncthreads();
    for (int i = t; i < CH; i += 512) {
        int e = e0 + i;
        if (e < n_edges) {
            int b = bk[i];
            int s = base[b] + atomicAdd(&lcur[b], 1);
            pay[s] = pl[i];
        }
    }
}

// ---------------- 5. bucket aggregate ----------------
__global__ __launch_bounds__(512) void k_baggr(const unsigned short* __restrict__ xb,
                                               const unsigned* __restrict__ pay,
                                               const int* __restrict__ bstart,
                                               unsigned short* __restrict__ hb, int num_dst) {
    __shared__ float acc[BROWS * F];   // 64 KB
    __shared__ int degl[BROWS];
    int t = threadIdx.x;
    for (int i = t; i < BROWS * F; i += 512) acc[i] = 0.0f;
    if (t < BROWS) degl[t] = 0;
    __syncthreads();

    int b = blockIdx.x;
    int s0 = bstart[b], s1 = bstart[b + 1];
    int wave = t >> 6, lane = t & 63;

    for (int i = s0 + wave * 2; i < s1; i += 16) {
        unsigned p0 = pay[i];
        bool has1 = (i + 1 < s1);
        unsigned p1 = has1 ? pay[i + 1] : p0;
        float v0 = bf2f(xb[(long)(p0 >> 8) * F + lane]);
        float v1 = bf2f(xb[(long)(p1 >> 8) * F + lane]);
        atomicAdd(&acc[(p0 & 255) * F + lane], v0);
        if (has1) atomicAdd(&acc[(p1 & 255) * F + lane], v1);
        if (lane == 0) {
            atomicAdd(&degl[p0 & 255], 1);
            if (has1) atomicAdd(&degl[p1 & 255], 1);
        }
    }
    __syncthreads();

    int r0 = b * BROWS;
    int rows = min(BROWS, num_dst - r0);
    for (int idx = t; idx < rows * F; idx += 512) {
        int r = idx >> 6;
        float inv = 1.0f / fmaxf((float)degl[r], 1.0f);
        hb[(long)r0 * F + idx] = f2bf(acc[idx] * inv);
    }
}

// ---------------- 6. fused dual-GEMM, bf16 MFMA ----------------
__global__ __launch_bounds__(256) void k_gemm_mfma(
    const unsigned short* __restrict__ xb, const unsigned short* __restrict__ hb,
    const float* __restrict__ Ws, const float* __restrict__ Wn,
    const float* __restrict__ b, float* __restrict__ out, int num_dst)
{
    __shared__ __align__(16) unsigned short Atile[64 * LDK];
    __shared__ __align__(16) unsigned short Wt[64 * LDK];
    int t = threadIdx.x;
    int row0 = blockIdx.x * 64;

    for (int i = t; i < 128 * 64; i += 256) {
        int k = i >> 6, n = i & 63;
        float v = (k < 64) ? Ws[k * 64 + n] : Wn[(k - 64) * 64 + n];
        Wt[n * LDK + k] = f2bf(v);
    }
    for (int i = t; i < 64 * 16; i += 256) {
        int r = i >> 4, s = i & 15;
        int g = row0 + r;
        short8 v = {0, 0, 0, 0, 0, 0, 0, 0};
        if (g < num_dst)
            v = (s < 8) ? *(const short8*)&xb[(long)g * F + s * 8]
                        : *(const short8*)&hb[(long)g * F + (s - 8) * 8];
        *(short8*)&Atile[r * LDK + s * 8] = v;
    }
    __syncthreads();

    int lane = t & 63;
    int wave = t >> 6;
    int m = lane & 15;
    int quad = lane >> 4;
    const unsigned short* arow = &Atile[(wave * 16 + m) * LDK + quad * 8];

    float4v acc[4];
#pragma unroll
    for (int nt = 0; nt < 4; ++nt) acc[nt] = (float4v){0.f, 0.f, 0.f, 0.f};

#pragma unroll
    for (int kb = 0; kb < 4; ++kb) {
        short8 a = *(const short8*)(arow + kb * 32);
#pragma unroll
        for (int nt = 0; nt < 4; ++nt) {
            short8 bf = *(const short8*)&Wt[(nt * 16 + m) * LDK + quad * 8 + kb * 32];
            acc[nt] = __builtin_amdgcn_mfma_f32_16x16x32_bf16(a, bf, acc[nt], 0, 0, 0);
        }
    }

    int gr_base = row0 + wave * 16 + quad * 4;
#pragma unroll
    for (int nt = 0; nt < 4; ++nt) {
        int col = nt * 16 + m;
        float bias = b[col];
#pragma unroll
        for (int rg = 0; rg < 4; ++rg) {
            int g = gr_base + rg;
            if (g < num_dst) out[(long)g * F + col] = fmaxf(acc[nt][rg] + bias, 0.0f);
        }
    }
}

// ---------------- fallback (R0, proven) ----------------
__global__ __launch_bounds__(256) void k_scatter(const float* __restrict__ x, const int* __restrict__ src,
                                                 const int* __restrict__ dst, float* __restrict__ summed,
                                                 float* __restrict__ degf, int n_edges) {
    long tid = (long)blockIdx.x * 256 + threadIdx.x;
    int e = (int)(tid >> 6);
    if (e >= n_edges) return;
    int f = threadIdx.x & 63;
    atomicAdd(&summed[(long)dst[e] * F + f], x[(long)src[e] * F + f]);
    if (f == 0) atomicAdd(&degf[dst[e]], 1.0f);
}

__global__ __launch_bounds__(256) void k_gemm_shfl(
    const float* __restrict__ x, const float* __restrict__ Ws, const float* __restrict__ Wn,
    const float* __restrict__ b, const float* __restrict__ degf, float* inout, int num_dst)
{
    __shared__ float Wl[2 * F * F];
    for (int i = threadIdx.x; i < F * F; i += 256) { Wl[i] = Ws[i]; Wl[F * F + i] = Wn[i]; }
    __syncthreads();
    int lane = threadIdx.x & 63;
    int r = (blockIdx.x * 256 + threadIdx.x) >> 6;
    if (r >= num_dst) return;
    float xv = x[(long)r * F + lane];
    float hv = inout[(long)r * F + lane] / fmaxf(degf[r], 1.0f);
    float acc = b[lane];
#pragma unroll
    for (int k = 0; k < F; ++k) {
        acc += __shfl(xv, k) * Wl[k * F + lane];
        acc += __shfl(hv, k) * Wl[(F + k) * F + lane];
    }
    inout[(long)r * F + lane] = fmaxf(acc, 0.0f);
}

// ---------------- launch ----------------
extern "C" void kernel_launch(void* const* d_in, const int* in_sizes, int n_in,
                              void* d_out, int out_size, void* d_ws, size_t ws_size,
                              hipStream_t stream) {
    const float* x  = (const float*)d_in[0];
    const float* Ws = (const float*)d_in[1];
    const float* Wn = (const float*)d_in[2];
    const float* b  = (const float*)d_in[3];
    const int* src  = (const int*)d_in[4];
    const int* dst  = (const int*)d_in[5];
    int n_edges = in_sizes[4];
    int num_dst = out_size / F;
    float* out = (float*)d_out;

    char* ws = (char*)d_ws;
    size_t off = 0;
    auto alloc = [&](size_t bytes) { char* p = ws + off; off = (off + bytes + 255) & ~(size_t)255; return p; };
    unsigned short* xb = (unsigned short*)alloc((size_t)num_dst * F * 2);
    unsigned short* hb = (unsigned short*)alloc((size_t)num_dst * F * 2);
    unsigned* pay      = (unsigned*)alloc((size_t)n_edges * 4);
    int* bcnt          = (int*)alloc((MAXNB + 1) * 4);
    int* bstart        = (int*)alloc((MAXNB + 1) * 4);
    int* bcur          = (int*)alloc((MAXNB + 1) * 4);
    int nb = (num_dst + BROWS - 1) / BROWS;
    bool big_ws = (off <= ws_size) && (nb <= MAXNB);

    if (big_ws) {
        (void)hipMemsetAsync(bcnt, 0, (MAXNB + 1) * 4, stream);

        long n4 = (long)num_dst * F / 4;
        k_tobf16<<<2048, 256, 0, stream>>>(x, xb, n4);
        k_bincount<<<128, 256, 0, stream>>>(dst, bcnt, n_edges);
        k_bscan<<<1, MAXNB, 0, stream>>>(bcnt, bstart, bcur, nb);
        int nblk = (n_edges + CH - 1) / CH;
        k_bpart<<<nblk, 512, 0, stream>>>(src, dst, bcur, pay, n_edges);
        k_baggr<<<nb, 512, 0, stream>>>(xb, pay, bstart, hb, num_dst);
        k_gemm_mfma<<<(num_dst + 63) / 64, 256, 0, stream>>>(xb, hb, Ws, Wn, b, out, num_dst);
    } else {
        float* degf = (float*)d_ws;
        (void)hipMemsetAsync(d_out, 0, (size_t)out_size * sizeof(float), stream);
        (void)hipMemsetAsync(degf, 0, (size_t)num_dst * sizeof(float), stream);
        long tt = (long)n_edges * 64;
        k_scatter<<<(int)((tt + 255) / 256), 256, 0, stream>>>(x, src, dst, out, degf, n_edges);
        k_gemm_shfl<<<(num_dst + 3) / 4, 256, 0, stream>>>(x, Ws, Wn, b, degf, out, num_dst);
    }
}

// Round 5
// 189.513 us; speedup vs baseline: 3.0643x; 3.0643x over previous
//
#include <hip/hip_runtime.h>

// SAGE layer: out = relu(x @ W_self + (segment_sum(x[src], dst)/max(deg,1)) @ W_neigh + b)
//
// R4: R3's k_baggr (448us: LDS float atomicAdd = CAS loops + 2 blocks/CU) replaced by
// atomic-free aggregation. All atomics in the pipeline are native int adds.
//   1. k_tobf16:    x (f32) -> xb (bf16)
//   2. k_bincount:  edges per 256-row dst bucket (int LDS hist)
//   3. k_bscan:     exclusive scan -> bucket starts/cursors
//   4. k_bpart:     partition edges into bucket-contiguous pay = (src<<8)|dst_local
//                   (per-(block,bucket) run reservation -> L2-merged writes)
//   5. k_csr:       block per bucket: int hist + scan -> exact CSR (block-owned region)
//   6. k_aggregate: wave per dst row, bf16 gathers, 4-way ILP f32 accumulate -> hb
//   7. k_gemm_mfma: A=[xb|hb] K=128, W=[Ws;Wn] bf16 MFMA, bias+relu (proven, absmax .031)
// Fallback (small ws): R0 atomic scatter + shfl gemm.

constexpr int F = 64;
constexpr int BROWS = 256;   // dst rows per bucket
constexpr int MAXNB = 512;   // max buckets (num_dst <= 131072)
constexpr int CHP = 4096;    // edges per partition block
constexpr int LDK = 136;     // 128 + 8 pad (bf16 elems)

typedef __attribute__((ext_vector_type(8))) short short8;
typedef __attribute__((ext_vector_type(4))) float float4v;

__device__ inline unsigned short f2bf(float f) {
    union { float f; unsigned u; } c; c.f = f;
    unsigned u = c.u;
    return (unsigned short)((u + 0x7FFFu + ((u >> 16) & 1u)) >> 16);  // RNE
}
__device__ inline float bf2f(unsigned short h) {
    union { unsigned u; float f; } c; c.u = (unsigned)h << 16;
    return c.f;
}

// ---------------- 1. convert x to bf16 ----------------
__global__ __launch_bounds__(256) void k_tobf16(const float* __restrict__ x,
                                                unsigned short* __restrict__ xb, long n4) {
    for (long i = (long)blockIdx.x * 256 + threadIdx.x; i < n4; i += (long)gridDim.x * 256) {
        float4 v = ((const float4*)x)[i];
        ushort4 o;
        o.x = f2bf(v.x); o.y = f2bf(v.y); o.z = f2bf(v.z); o.w = f2bf(v.w);
        ((ushort4*)xb)[i] = o;
    }
}

// ---------------- 2. bucket histogram ----------------
__global__ __launch_bounds__(256) void k_bincount(const int* __restrict__ dst,
                                                  int* __restrict__ bcnt, int n_edges) {
    __shared__ int h[MAXNB];
    for (int i = threadIdx.x; i < MAXNB; i += 256) h[i] = 0;
    __syncthreads();
    for (int e = blockIdx.x * 256 + threadIdx.x; e < n_edges; e += gridDim.x * 256)
        atomicAdd(&h[dst[e] >> 8], 1);
    __syncthreads();
    for (int i = threadIdx.x; i < MAXNB; i += 256)
        if (h[i]) atomicAdd(&bcnt[i], h[i]);
}

// ---------------- 3. scan over buckets ----------------
__global__ __launch_bounds__(512) void k_bscan(const int* __restrict__ bcnt,
                                               int* __restrict__ bstart,
                                               int* __restrict__ bcur, int nb) {
    __shared__ int buf[MAXNB];
    int t = threadIdx.x;
    int v = bcnt[t];
    buf[t] = v; __syncthreads();
    for (int off = 1; off < MAXNB; off <<= 1) {
        int tv = (t >= off) ? buf[t - off] : 0;
        __syncthreads();
        buf[t] += tv;
        __syncthreads();
    }
    int ex = buf[t] - v;
    if (t < nb) { bstart[t] = ex; bcur[t] = ex; }
    if (t == MAXNB - 1) bstart[nb] = buf[MAXNB - 1];
}

// ---------------- 4. partition into buckets ----------------
__global__ __launch_bounds__(256) void k_bpart(const int* __restrict__ src,
                                               const int* __restrict__ dst,
                                               int* __restrict__ bcur,
                                               unsigned* __restrict__ pay, int n_edges) {
    __shared__ int hist[MAXNB];
    __shared__ int base[MAXNB];
    __shared__ int lcur[MAXNB];
    int t = threadIdx.x;
    int e0 = blockIdx.x * CHP;
    int e1 = min(e0 + CHP, n_edges);
    for (int i = t; i < MAXNB; i += 256) { hist[i] = 0; lcur[i] = 0; }
    __syncthreads();
    for (int e = e0 + t; e < e1; e += 256) atomicAdd(&hist[dst[e] >> 8], 1);
    __syncthreads();
    for (int i = t; i < MAXNB; i += 256)
        if (hist[i]) base[i] = atomicAdd(&bcur[i], hist[i]);
    __syncthreads();
    for (int e = e0 + t; e < e1; e += 256) {
        int d = dst[e];
        int b = d >> 8;
        int pos = base[b] + atomicAdd(&lcur[b], 1);
        pay[pos] = ((unsigned)src[e] << 8) | (unsigned)(d & 255);
    }
}

// ---------------- 5. per-bucket exact CSR ----------------
__global__ __launch_bounds__(256) void k_csr(const unsigned* __restrict__ pay,
                                             const int* __restrict__ bstart,
                                             int* __restrict__ row_start,
                                             int* __restrict__ csr,
                                             int num_dst, int n_edges, int nb) {
    __shared__ int hist[BROWS];
    __shared__ int scn[BROWS];
    int t = threadIdx.x;
    int b = blockIdx.x;
    int s0 = bstart[b], s1 = bstart[b + 1];
    hist[t] = 0;
    __syncthreads();
    for (int i = s0 + t; i < s1; i += 256) atomicAdd(&hist[pay[i] & 255], 1);
    __syncthreads();
    int v = hist[t];
    scn[t] = v;
    __syncthreads();
    for (int off = 1; off < 256; off <<= 1) {
        int tv = (t >= off) ? scn[t - off] : 0;
        __syncthreads();
        scn[t] += tv;
        __syncthreads();
    }
    int excl = scn[t] - v;
    int r0 = b * BROWS;
    if (r0 + t < num_dst) row_start[r0 + t] = s0 + excl;
    if (b == nb - 1 && t == 0) row_start[num_dst] = n_edges;
    hist[t] = excl;   // reuse as cursor
    __syncthreads();
    for (int i = s0 + t; i < s1; i += 256) {
        unsigned p = pay[i];
        int pos = atomicAdd(&hist[p & 255], 1);
        csr[s0 + pos] = (int)(p >> 8);
    }
}

// ---------------- 6. aggregate: wave per dst row, 4-way ILP ----------------
__global__ __launch_bounds__(256) void k_aggregate(const unsigned short* __restrict__ xb,
                                                   const int* __restrict__ row_start,
                                                   const int* __restrict__ csr,
                                                   unsigned short* __restrict__ hb, int num_dst) {
    int lane = threadIdx.x & 63;
    int r = (blockIdx.x * 256 + threadIdx.x) >> 6;
    if (r >= num_dst) return;
    int s0 = row_start[r], s1 = row_start[r + 1];
    float a0 = 0.f, a1 = 0.f, a2 = 0.f, a3 = 0.f;
    for (int base = s0; base < s1; base += 64) {
        int sid = (base + lane < s1) ? csr[base + lane] : 0;
        int n = min(64, s1 - base);
        int i = 0;
        for (; i + 3 < n; i += 4) {
            int e0 = __shfl(sid, i), e1 = __shfl(sid, i + 1);
            int e2 = __shfl(sid, i + 2), e3 = __shfl(sid, i + 3);
            a0 += bf2f(xb[(long)e0 * F + lane]);
            a1 += bf2f(xb[(long)e1 * F + lane]);
            a2 += bf2f(xb[(long)e2 * F + lane]);
            a3 += bf2f(xb[(long)e3 * F + lane]);
        }
        for (; i < n; ++i) a0 += bf2f(xb[(long)__shfl(sid, i) * F + lane]);
    }
    float deg = (float)(s1 - s0);
    float s = (a0 + a1) + (a2 + a3);
    hb[(long)r * F + lane] = f2bf(s / fmaxf(deg, 1.0f));
}

// ---------------- 7. fused dual-GEMM, bf16 MFMA ----------------
__global__ __launch_bounds__(256) void k_gemm_mfma(
    const unsigned short* __restrict__ xb, const unsigned short* __restrict__ hb,
    const float* __restrict__ Ws, const float* __restrict__ Wn,
    const float* __restrict__ b, float* __restrict__ out, int num_dst)
{
    __shared__ __align__(16) unsigned short Atile[64 * LDK];
    __shared__ __align__(16) unsigned short Wt[64 * LDK];
    int t = threadIdx.x;
    int row0 = blockIdx.x * 64;

    for (int i = t; i < 128 * 64; i += 256) {
        int k = i >> 6, n = i & 63;
        float v = (k < 64) ? Ws[k * 64 + n] : Wn[(k - 64) * 64 + n];
        Wt[n * LDK + k] = f2bf(v);
    }
    for (int i = t; i < 64 * 16; i += 256) {
        int r = i >> 4, s = i & 15;
        int g = row0 + r;
        short8 v = {0, 0, 0, 0, 0, 0, 0, 0};
        if (g < num_dst)
            v = (s < 8) ? *(const short8*)&xb[(long)g * F + s * 8]
                        : *(const short8*)&hb[(long)g * F + (s - 8) * 8];
        *(short8*)&Atile[r * LDK + s * 8] = v;
    }
    __syncthreads();

    int lane = t & 63;
    int wave = t >> 6;
    int m = lane & 15;
    int quad = lane >> 4;
    const unsigned short* arow = &Atile[(wave * 16 + m) * LDK + quad * 8];

    float4v acc[4];
#pragma unroll
    for (int nt = 0; nt < 4; ++nt) acc[nt] = (float4v){0.f, 0.f, 0.f, 0.f};

#pragma unroll
    for (int kb = 0; kb < 4; ++kb) {
        short8 a = *(const short8*)(arow + kb * 32);
#pragma unroll
        for (int nt = 0; nt < 4; ++nt) {
            short8 bf = *(const short8*)&Wt[(nt * 16 + m) * LDK + quad * 8 + kb * 32];
            acc[nt] = __builtin_amdgcn_mfma_f32_16x16x32_bf16(a, bf, acc[nt], 0, 0, 0);
        }
    }

    int gr_base = row0 + wave * 16 + quad * 4;
#pragma unroll
    for (int nt = 0; nt < 4; ++nt) {
        int col = nt * 16 + m;
        float bias = b[col];
#pragma unroll
        for (int rg = 0; rg < 4; ++rg) {
            int g = gr_base + rg;
            if (g < num_dst) out[(long)g * F + col] = fmaxf(acc[nt][rg] + bias, 0.0f);
        }
    }
}

// ---------------- fallback (R0, proven) ----------------
__global__ __launch_bounds__(256) void k_scatter(const float* __restrict__ x, const int* __restrict__ src,
                                                 const int* __restrict__ dst, float* __restrict__ summed,
                                                 float* __restrict__ degf, int n_edges) {
    long tid = (long)blockIdx.x * 256 + threadIdx.x;
    int e = (int)(tid >> 6);
    if (e >= n_edges) return;
    int f = threadIdx.x & 63;
    atomicAdd(&summed[(long)dst[e] * F + f], x[(long)src[e] * F + f]);
    if (f == 0) atomicAdd(&degf[dst[e]], 1.0f);
}

__global__ __launch_bounds__(256) void k_gemm_shfl(
    const float* __restrict__ x, const float* __restrict__ Ws, const float* __restrict__ Wn,
    const float* __restrict__ b, const float* __restrict__ degf, float* inout, int num_dst)
{
    __shared__ float Wl[2 * F * F];
    for (int i = threadIdx.x; i < F * F; i += 256) { Wl[i] = Ws[i]; Wl[F * F + i] = Wn[i]; }
    __syncthreads();
    int lane = threadIdx.x & 63;
    int r = (blockIdx.x * 256 + threadIdx.x) >> 6;
    if (r >= num_dst) return;
    float xv = x[(long)r * F + lane];
    float hv = inout[(long)r * F + lane] / fmaxf(degf[r], 1.0f);
    float acc = b[lane];
#pragma unroll
    for (int k = 0; k < F; ++k) {
        acc += __shfl(xv, k) * Wl[k * F + lane];
        acc += __shfl(hv, k) * Wl[(F + k) * F + lane];
    }
    inout[(long)r * F + lane] = fmaxf(acc, 0.0f);
}

// ---------------- launch ----------------
extern "C" void kernel_launch(void* const* d_in, const int* in_sizes, int n_in,
                              void* d_out, int out_size, void* d_ws, size_t ws_size,
                              hipStream_t stream) {
    const float* x  = (const float*)d_in[0];
    const float* Ws = (const float*)d_in[1];
    const float* Wn = (const float*)d_in[2];
    const float* b  = (const float*)d_in[3];
    const int* src  = (const int*)d_in[4];
    const int* dst  = (const int*)d_in[5];
    int n_edges = in_sizes[4];
    int num_dst = out_size / F;
    float* out = (float*)d_out;

    char* ws = (char*)d_ws;
    size_t off = 0;
    auto alloc = [&](size_t bytes) { char* p = ws + off; off = (off + bytes + 255) & ~(size_t)255; return p; };
    unsigned short* xb = (unsigned short*)alloc((size_t)num_dst * F * 2);
    unsigned short* hb = (unsigned short*)alloc((size_t)num_dst * F * 2);
    unsigned* pay      = (unsigned*)alloc((size_t)n_edges * 4);
    int* csr           = (int*)alloc((size_t)n_edges * 4);
    int* row_start     = (int*)alloc((size_t)(num_dst + 1) * 4);
    int* bcnt          = (int*)alloc((MAXNB + 1) * 4);
    int* bstart        = (int*)alloc((MAXNB + 1) * 4);
    int* bcur          = (int*)alloc((MAXNB + 1) * 4);
    int nb = (num_dst + BROWS - 1) / BROWS;
    bool big_ws = (off <= ws_size) && (nb <= MAXNB);

    if (big_ws) {
        (void)hipMemsetAsync(bcnt, 0, (MAXNB + 1) * 4, stream);

        long n4 = (long)num_dst * F / 4;
        k_tobf16<<<2048, 256, 0, stream>>>(x, xb, n4);
        k_bincount<<<256, 256, 0, stream>>>(dst, bcnt, n_edges);
        k_bscan<<<1, MAXNB, 0, stream>>>(bcnt, bstart, bcur, nb);
        k_bpart<<<(n_edges + CHP - 1) / CHP, 256, 0, stream>>>(src, dst, bcur, pay, n_edges);
        k_csr<<<nb, 256, 0, stream>>>(pay, bstart, row_start, csr, num_dst, n_edges, nb);
        k_aggregate<<<(num_dst + 3) / 4, 256, 0, stream>>>(xb, row_start, csr, hb, num_dst);
        k_gemm_mfma<<<(num_dst + 63) / 64, 256, 0, stream>>>(xb, hb, Ws, Wn, b, out, num_dst);
    } else {
        float* degf = (float*)d_ws;
        (void)hipMemsetAsync(d_out, 0, (size_t)out_size * sizeof(float), stream);
        (void)hipMemsetAsync(degf, 0, (size_t)num_dst * sizeof(float), stream);
        long tt = (long)n_edges * 64;
        k_scatter<<<(int)((tt + 255) / 256), 256, 0, stream>>>(x, src, dst, out, degf, n_edges);
        k_gemm_shfl<<<(num_dst + 3) / 4, 256, 0, stream>>>(x, Ws, Wn, b, degf, out, num_dst);
    }
}